// Round 3
// baseline (587.882 us; speedup 1.0000x reference)
//
#include <hip/hip_runtime.h>

// VQ-VAE vector quantization forward — bit-exact emulation of the numpy ref.
// x: [32,64,64,64] f32 -> flat [N=131072, D=64]; embeddings: [D=64, K=512].
//
// np numerics matched exactly (validated round 2, absmax 0.0):
//   A   = np.sum(f*f, axis=1)   -> pairwise scalar 8-accumulator path (n=64)
//   B_k = np.sum(e*e, axis=0)   -> sequential over d, separate mul+add
//   sim = flat @ emb            -> sequential FMA chain over d per code
//   dist_k = fl( fl(A + B_k) - fl(2*sim_k) ), argmin = first min
// out = fl(x + fl(q - x)); loss = 1.25 * mean((q-x)^2)
//
// Round 3 perf changes (numerics untouched):
//  - K split 4-ways: block = 256 thr = 64 rows x 4 k-quarters (quarter == wave
//    => emb/e2 addresses remain wave-uniform -> scalar broadcast loads).
//    8192 waves total (was 2048) -> latency hiding. Exact first-min combine in
//    LDS: (d < best) || (d == best && idx < bestidx).
//  - __launch_bounds__(256, 4): 128-VGPR budget so f[64] stays in registers
//    (round 2: VGPR=56 proved the compiler was re-loading f from L1 per chunk).
//  - Coalesced cooperative epilogue over the block's 64x64 output tile.

constexpr int D = 64;
constexpr int K = 512;
constexpr int NROWS = 131072;           // 32*64*64*64 / 64
constexpr long long NELEM = 8388608LL;  // NROWS * D
constexpr int ROWS_PER_BLOCK = 64;
constexpr int KQ = 128;                 // codes per quarter

// B_k = ||e_k||^2, sequential non-FMA over d (numpy axis-0 reduction order).
__global__ __launch_bounds__(512) void vq_prep(const float* __restrict__ emb,
                                               float* __restrict__ e2,
                                               float* __restrict__ loss_acc) {
    int k = threadIdx.x;  // 0..511
    float e0 = emb[k];
    float b = __fmul_rn(e0, e0);
    for (int d = 1; d < D; ++d) {
        float e = emb[d * K + k];
        b = __fadd_rn(b, __fmul_rn(e, e));
    }
    e2[k] = b;
    if (k == 0) loss_acc[0] = 0.f;
}

__global__ __launch_bounds__(256, 4) void vq_main(const float* __restrict__ x,
                                                  const float* __restrict__ emb,
                                                  const float* __restrict__ e2,
                                                  float* __restrict__ out,
                                                  float* __restrict__ loss_acc) {
    const int tid = threadIdx.x;
    const int q = tid >> 6;    // k-quarter == wave index (wave-uniform)
    const int r = tid & 63;    // row within block
    const int row = blockIdx.x * ROWS_PER_BLOCK + r;
    const float* xr = x + (size_t)row * D;

    // Row into registers (16 x float4). 4 waves (quarters) share these rows
    // -> L1 reuse; block footprint 16 KB fits L1.
    float f[D];
    const float4* xr4 = reinterpret_cast<const float4*>(xr);
#pragma unroll
    for (int j = 0; j < D / 4; ++j) {
        float4 v = xr4[j];
        f[4 * j + 0] = v.x;
        f[4 * j + 1] = v.y;
        f[4 * j + 2] = v.z;
        f[4 * j + 3] = v.w;
    }

    // A = numpy pairwise sum of f*f (n=64 scalar 8-accumulator path).
    float rr[8];
#pragma unroll
    for (int j = 0; j < 8; ++j) rr[j] = __fmul_rn(f[j], f[j]);
#pragma unroll
    for (int i = 8; i < D; i += 8)
#pragma unroll
        for (int j = 0; j < 8; ++j)
            rr[j] = __fadd_rn(rr[j], __fmul_rn(f[i + j], f[i + j]));
    const float A =
        __fadd_rn(__fadd_rn(__fadd_rn(rr[0], rr[1]), __fadd_rn(rr[2], rr[3])),
                  __fadd_rn(__fadd_rn(rr[4], rr[5]), __fadd_rn(rr[6], rr[7])));

    // Partial argmin over this quarter's 128 codes. emb/e2 addresses are
    // wave-uniform (q, k0, d loop-derived) -> scalar broadcast loads.
    float best = 3.0e38f;
    int bidx = 0;
    const int kbase = q * KQ;
    for (int k0 = kbase; k0 < kbase + KQ; k0 += 8) {
        float acc[8];
#pragma unroll
        for (int kk = 0; kk < 8; ++kk) acc[kk] = 0.f;
#pragma unroll
        for (int d = 0; d < D; ++d) {
            const float fd = f[d];
            const float* er = emb + d * K + k0;  // uniform
#pragma unroll
            for (int kk = 0; kk < 8; ++kk)
                acc[kk] = __fmaf_rn(fd, er[kk], acc[kk]);
        }
#pragma unroll
        for (int kk = 0; kk < 8; ++kk) {
            float dist = __fsub_rn(__fadd_rn(A, e2[k0 + kk]),
                                   __fmul_rn(2.0f, acc[kk]));
            if (dist < best) {  // strict <: first-min within quarter
                best = dist;
                bidx = k0 + kk;
            }
        }
    }

    // Exact cross-quarter combine (first-min tiebreak: equal dist -> lower k,
    // and quarters scan in ascending k order).
    __shared__ float sdist[4][ROWS_PER_BLOCK];
    __shared__ int sidx[4][ROWS_PER_BLOCK];
    __shared__ int bx[ROWS_PER_BLOCK];
    sdist[q][r] = best;
    sidx[q][r] = bidx;
    __syncthreads();
    if (tid < ROWS_PER_BLOCK) {
        float b0 = sdist[0][tid];
        int i0 = sidx[0][tid];
#pragma unroll
        for (int qq = 1; qq < 4; ++qq) {
            float dq = sdist[qq][tid];
            int iq = sidx[qq][tid];
            if (dq < b0) { b0 = dq; i0 = iq; }
            // dq == b0 -> keep i0 (lower k). dq > b0 -> keep. Exact.
        }
        bx[tid] = i0;
    }
    __syncthreads();

    // Cooperative epilogue: block tile = 64 rows x 64 floats = 1024 float4.
    // e4 = j*256 + tid -> lane-contiguous 16B stores (coalesced).
    float lsum = 0.f;
#pragma unroll
    for (int j = 0; j < 4; ++j) {
        const int e4 = j * 256 + tid;       // float4 index in tile
        const int rr2 = e4 >> 4;            // row in block (16 float4/row)
        const int d0 = (e4 & 15) * 4;
        const size_t gbase = (size_t)(blockIdx.x * ROWS_PER_BLOCK + rr2) * D + d0;
        const float4 xv = *reinterpret_cast<const float4*>(x + gbase);
        const int bi = bx[rr2];
        const float* eq = emb + bi;
        float4 o;
        float qv, t;
        qv = eq[(d0 + 0) * K]; t = __fsub_rn(qv, xv.x);
        lsum = __fmaf_rn(t, t, lsum); o.x = __fadd_rn(xv.x, t);
        qv = eq[(d0 + 1) * K]; t = __fsub_rn(qv, xv.y);
        lsum = __fmaf_rn(t, t, lsum); o.y = __fadd_rn(xv.y, t);
        qv = eq[(d0 + 2) * K]; t = __fsub_rn(qv, xv.z);
        lsum = __fmaf_rn(t, t, lsum); o.z = __fadd_rn(xv.z, t);
        qv = eq[(d0 + 3) * K]; t = __fsub_rn(qv, xv.w);
        lsum = __fmaf_rn(t, t, lsum); o.w = __fadd_rn(xv.w, t);
        *reinterpret_cast<float4*>(out + gbase) = o;
    }

    // Loss reduce: wave shuffle -> LDS across 4 waves -> one atomic per block.
#pragma unroll
    for (int off = 32; off > 0; off >>= 1) lsum += __shfl_down(lsum, off, 64);
    __shared__ float wsum[4];
    if (r == 0) wsum[q] = lsum;
    __syncthreads();
    if (tid == 0)
        atomicAdd(loss_acc, wsum[0] + wsum[1] + wsum[2] + wsum[3]);
}

__global__ void vq_finalize(const float* __restrict__ loss_acc,
                            float* __restrict__ out_loss) {
    if (threadIdx.x == 0) {
        float m = loss_acc[0] / (float)NELEM;  // /2^23: exact
        out_loss[0] = 1.25f * m;               // == fl(0.25m + m)
    }
}

extern "C" void kernel_launch(void* const* d_in, const int* in_sizes, int n_in,
                              void* d_out, int out_size, void* d_ws, size_t ws_size,
                              hipStream_t stream) {
    const float* x = (const float*)d_in[0];
    const float* emb = (const float*)d_in[1];
    float* out = (float*)d_out;

    float* ws = (float*)d_ws;
    float* loss_acc = ws;      // 1 float
    float* e2 = ws + 64;       // 512 floats

    vq_prep<<<1, 512, 0, stream>>>(emb, e2, loss_acc);
    vq_main<<<NROWS / ROWS_PER_BLOCK, 256, 0, stream>>>(x, emb, e2, out, loss_acc);
    vq_finalize<<<1, 64, 0, stream>>>(loss_acc, out + NELEM);
}

// Round 4
// 292.025 us; speedup vs baseline: 2.0131x; 2.0131x over previous
//
#include <hip/hip_runtime.h>

// VQ-VAE vector quantization forward — bit-exact emulation of the numpy ref.
// x: [32,64,64,64] f32 -> flat [N=131072, D=64]; embeddings: [D=64, K=512].
//
// np numerics matched exactly (validated round 2, absmax 0.0):
//   A   = np.sum(f*f, axis=1)   -> pairwise scalar 8-accumulator path (n=64)
//   B_k = np.sum(e*e, axis=0)   -> sequential over d, separate mul+add
//   sim = flat @ emb            -> sequential FMA chain over d per code
//   dist_k = fl( fl(A + B_k) - fl(2*sim_k) ), argmin = first min
// out = fl(x + fl(q - x)); loss = 1.25 * mean((q-x)^2)
//
// Round 4: round-2 structure (thread-per-row, k loop wave-uniform -> scalar
// emb broadcast loads) + the one fix the counters demanded:
//  - PIN f[64] in VGPRs via opaque asm ("+v"). Rounds 2/3 showed VGPR=52-56:
//    the allocator rematerialized f[d] from global inside the k-loop — a
//    64-lane scatter (lane=row, 256B stride) re-touching ~16KB/wave/chunk.
//    asm results can't be rematerialized as loads -> row stays resident.
//  - __launch_bounds__(256, 3): VGPR budget ~170 (need ~110), 3 waves/SIMD
//    for SMEM latency hiding.
// Round-3 lesson kept: NO threadIdx-derived k partitioning (q=tid>>6 is not
// provably uniform -> emb loads degrade to vector gathers, VALUBusy 29%).

constexpr int D = 64;
constexpr int K = 512;
constexpr int NROWS = 131072;           // 32*64*64*64 / 64
constexpr long long NELEM = 8388608LL;  // NROWS * D

// B_k = ||e_k||^2, sequential non-FMA over d (numpy axis-0 reduction order).
__global__ __launch_bounds__(512) void vq_prep(const float* __restrict__ emb,
                                               float* __restrict__ e2,
                                               float* __restrict__ loss_acc) {
    int k = threadIdx.x;  // 0..511
    float e0 = emb[k];
    float b = __fmul_rn(e0, e0);
    for (int d = 1; d < D; ++d) {
        float e = emb[d * K + k];
        b = __fadd_rn(b, __fmul_rn(e, e));
    }
    e2[k] = b;
    if (k == 0) loss_acc[0] = 0.f;
}

__global__ __launch_bounds__(256, 3) void vq_main(const float* __restrict__ x,
                                                  const float* __restrict__ emb,
                                                  const float* __restrict__ e2,
                                                  float* __restrict__ out,
                                                  float* __restrict__ loss_acc) {
    const int row = blockIdx.x * 256 + threadIdx.x;  // grid covers NROWS exactly
    const float* xr = x + (size_t)row * D;

    // Row into registers (16 x float4, coalesced), then PIN each element in a
    // VGPR: the asm output is opaque (not rematerializable), so the k-loop
    // below reads registers instead of re-scattering from L1/L2 every chunk.
    float f[D];
    const float4* xr4 = reinterpret_cast<const float4*>(xr);
#pragma unroll
    for (int j = 0; j < D / 4; ++j) {
        float4 v = xr4[j];
        f[4 * j + 0] = v.x;
        f[4 * j + 1] = v.y;
        f[4 * j + 2] = v.z;
        f[4 * j + 3] = v.w;
    }
#pragma unroll
    for (int i = 0; i < D; ++i) asm volatile("" : "+v"(f[i]));

    // A = numpy pairwise sum of f*f (n=64 scalar 8-accumulator path).
    float rr[8];
#pragma unroll
    for (int j = 0; j < 8; ++j) rr[j] = __fmul_rn(f[j], f[j]);
#pragma unroll
    for (int i = 8; i < D; i += 8)
#pragma unroll
        for (int j = 0; j < 8; ++j)
            rr[j] = __fadd_rn(rr[j], __fmul_rn(f[i + j], f[i + j]));
    const float A =
        __fadd_rn(__fadd_rn(__fadd_rn(rr[0], rr[1]), __fadd_rn(rr[2], rr[3])),
                  __fadd_rn(__fadd_rn(rr[4], rr[5]), __fadd_rn(rr[6], rr[7])));

    float best = 3.0e38f;
    int bidx = 0;
    // k in chunks of 8; all emb/e2 addresses loop-derived (wave-uniform)
    // -> s_load broadcast; inner body is pure v_fmac.
    for (int k0 = 0; k0 < K; k0 += 8) {
        float acc[8];
#pragma unroll
        for (int kk = 0; kk < 8; ++kk) acc[kk] = 0.f;
#pragma unroll
        for (int d = 0; d < D; ++d) {
            const float fd = f[d];
            const float* er = emb + d * K + k0;  // uniform
#pragma unroll
            for (int kk = 0; kk < 8; ++kk)
                acc[kk] = __fmaf_rn(fd, er[kk], acc[kk]);
        }
#pragma unroll
        for (int kk = 0; kk < 8; ++kk) {
            // dist = fl( fl(A + B) - fl(2*sim) )  -- exact np expression order
            float dist = __fsub_rn(__fadd_rn(A, e2[k0 + kk]),
                                   __fmul_rn(2.0f, acc[kk]));
            if (dist < best) {  // strict <: first-min tiebreak == np.argmin
                best = dist;
                bidx = k0 + kk;
            }
        }
    }

    // Gather winning column, write out = fl(x + fl(q-x)), accumulate loss.
    float lsum = 0.f;
    float* outr = out + (size_t)row * D;
    const float* eq = emb + bidx;
#pragma unroll
    for (int j = 0; j < D / 4; ++j) {
        float4 o;
        float q, t;
        q = eq[(4 * j + 0) * K]; t = __fsub_rn(q, f[4 * j + 0]);
        lsum = __fmaf_rn(t, t, lsum); o.x = __fadd_rn(f[4 * j + 0], t);
        q = eq[(4 * j + 1) * K]; t = __fsub_rn(q, f[4 * j + 1]);
        lsum = __fmaf_rn(t, t, lsum); o.y = __fadd_rn(f[4 * j + 1], t);
        q = eq[(4 * j + 2) * K]; t = __fsub_rn(q, f[4 * j + 2]);
        lsum = __fmaf_rn(t, t, lsum); o.z = __fadd_rn(f[4 * j + 2], t);
        q = eq[(4 * j + 3) * K]; t = __fsub_rn(q, f[4 * j + 3]);
        lsum = __fmaf_rn(t, t, lsum); o.w = __fadd_rn(f[4 * j + 3], t);
        reinterpret_cast<float4*>(outr)[j] = o;
    }

    // Loss reduce: wave shuffle -> LDS across 4 waves -> one atomic per block.
#pragma unroll
    for (int off = 32; off > 0; off >>= 1) lsum += __shfl_down(lsum, off, 64);
    __shared__ float wsum[4];
    const int lane = threadIdx.x & 63;
    const int wv = threadIdx.x >> 6;
    if (lane == 0) wsum[wv] = lsum;
    __syncthreads();
    if (threadIdx.x == 0)
        atomicAdd(loss_acc, wsum[0] + wsum[1] + wsum[2] + wsum[3]);
}

__global__ void vq_finalize(const float* __restrict__ loss_acc,
                            float* __restrict__ out_loss) {
    if (threadIdx.x == 0) {
        float m = loss_acc[0] / (float)NELEM;  // /2^23: exact
        out_loss[0] = 1.25f * m;               // == fl(0.25m + m)
    }
}

extern "C" void kernel_launch(void* const* d_in, const int* in_sizes, int n_in,
                              void* d_out, int out_size, void* d_ws, size_t ws_size,
                              hipStream_t stream) {
    const float* x = (const float*)d_in[0];
    const float* emb = (const float*)d_in[1];
    float* out = (float*)d_out;

    float* ws = (float*)d_ws;
    float* loss_acc = ws;      // 1 float
    float* e2 = ws + 64;       // 512 floats

    vq_prep<<<1, 512, 0, stream>>>(emb, e2, loss_acc);
    vq_main<<<NROWS / 256, 256, 0, stream>>>(x, emb, e2, out, loss_acc);
    vq_finalize<<<1, 64, 0, stream>>>(loss_acc, out + NELEM);
}